// Round 2
// baseline (7919.077 us; speedup 1.0000x reference)
//
#include <hip/hip_runtime.h>
#include <cmath>

namespace {
constexpr int Vv  = 10000;
constexpr int Ee  = 512;
constexpr int Hh  = 1024;
constexpr int Bb  = 128;
constexpr int Tt  = 64;
constexpr int CTX = 4096;
constexpr int Gg  = 4096;   // 4*H
constexpr int KIN1 = 4608;  // E + CTX
constexpr int TN  = 128;    // N tile per gemm block
constexpr int SL  = 16;     // K-slices for lstm/base gemms
constexpr int SV  = 4;      // K-slices for logits gemm
constexpr int K1c = Ee + Hh;   // 1536: [x | h1]
constexpr int K2c = 2 * Hh;    // 2048: [h1 | h2]
constexpr int NW1 = Gg * K1c;  // presplit ranges
constexpr int NW2 = Gg * K2c;
constexpr int NW3 = Vv * Hh;
}

typedef __bf16 bf16x8 __attribute__((ext_vector_type(8)));
typedef float  f32x4  __attribute__((ext_vector_type(4)));

// ---- fp32 -> (hi,lo) bf16 split, RNE both halves --------------------------
__device__ __forceinline__ unsigned rne16(unsigned u) {
  return (u + 0x7FFFu + ((u >> 16) & 1u)) >> 16;
}
__device__ __forceinline__ void split1(float x, unsigned short& h, unsigned short& l) {
  const unsigned uh = rne16(__float_as_uint(x));
  const float r = x - __uint_as_float(uh << 16);
  const unsigned ul = rne16(__float_as_uint(r));
  h = (unsigned short)uh; l = (unsigned short)ul;
}
__device__ __forceinline__ void split2(float x0, float x1,
                                       unsigned& hi, unsigned& lo) {
  const unsigned h0 = rne16(__float_as_uint(x0));
  const unsigned h1 = rne16(__float_as_uint(x1));
  hi = h0 | (h1 << 16);
  const float r0 = x0 - __uint_as_float(h0 << 16);
  const float r1 = x1 - __uint_as_float(h1 << 16);
  const unsigned l0 = rne16(__float_as_uint(r0));
  const unsigned l1 = rne16(__float_as_uint(r1));
  lo = l0 | (l1 << 16);
}

// ---------------------------------------------------------------------------
// Main-loop GEMM on pre-split bf16 hi/lo inputs (no conversion VALU).
// partial[slice][0:128][n0:n0+128] = A[0:128][kslice] @ W[n0:n0+128][kslice]^T
// 3-term: Ah*Wh + Al*Wh + Ah*Wl.  512 thr = 8 waves (2M x 4N), wave tile 64x32.
// A fragments load global->reg directly (A is L2-resident, <=1MB).
// W staged through padded LDS (reg-staged, prefetched one chunk ahead).
// ---------------------------------------------------------------------------
__global__ __launch_bounds__(512, 4) void gemm_bf16(
    const unsigned short* __restrict__ Ah, const unsigned short* __restrict__ Al, int lda,
    const unsigned short* __restrict__ Wh, const unsigned short* __restrict__ Wl, int ldw,
    int nrows, int kPerSlice,
    float* __restrict__ partial, int ldp)
{
  __shared__ unsigned short Whs[128][40];   // +8 pad: conflict-free b128 reads
  __shared__ unsigned short Wls[128][40];

  const int tid = threadIdx.x;
  const int n0  = blockIdx.x * TN;
  const int ks  = blockIdx.y * kPerSlice;
  const int nc  = kPerSlice >> 5;
  float* __restrict__ pout = partial + (size_t)blockIdx.y * (size_t)Bb * ldp;

  const int lane = tid & 63;
  const int wid  = tid >> 6;           // 0..7
  const int wm   = (wid >> 2) * 64;    // 0 / 64
  const int wn   = (wid & 3) * 32;     // 0 / 32 / 64 / 96
  const int fr   = lane & 15;
  const int koff = (lane >> 4) << 3;   // 0/8/16/24

  // W staging: each thread stages 16B of Wh and 16B of Wl per chunk
  const int sr  = tid >> 2;            // row 0..127
  const int seg = tid & 3;             // 16B segment 0..3
  const bool wok = (n0 + sr) < nrows;
  const unsigned short* wph = Wh + (size_t)(n0 + sr) * ldw + ks + seg * 8;
  const unsigned short* wpl = Wl + (size_t)(n0 + sr) * ldw + ks + seg * 8;

  f32x4 acc[4][2];
#pragma unroll
  for (int i = 0; i < 4; ++i)
#pragma unroll
    for (int j = 0; j < 2; ++j) acc[i][j] = f32x4{0.f, 0.f, 0.f, 0.f};

  uint4 whr = wok ? *(const uint4*)wph : uint4{0u, 0u, 0u, 0u};
  uint4 wlr = wok ? *(const uint4*)wpl : uint4{0u, 0u, 0u, 0u};

  // A fragment base (per-lane): row wm+fr, advance 16 rows per mf
  const unsigned short* aph = Ah + (size_t)(wm + fr) * lda + ks + koff;
  const unsigned short* apl = Al + (size_t)(wm + fr) * lda + ks + koff;

  for (int c = 0; c < nc; ++c) {
    __syncthreads();                         // prior compute done
    *(uint4*)&Whs[sr][seg * 8] = whr;
    *(uint4*)&Wls[sr][seg * 8] = wlr;
    __syncthreads();
    if (c + 1 < nc) {                        // prefetch next W chunk
      const int o = (c + 1) << 5;
      whr = wok ? *(const uint4*)(wph + o) : uint4{0u, 0u, 0u, 0u};
      wlr = wok ? *(const uint4*)(wpl + o) : uint4{0u, 0u, 0u, 0u};
    }
    const int co = c << 5;
    bf16x8 ahf[4], alf[4];
#pragma unroll
    for (int mf = 0; mf < 4; ++mf) {
      ahf[mf] = *(const bf16x8*)(aph + (size_t)mf * 16 * lda + co);
      alf[mf] = *(const bf16x8*)(apl + (size_t)mf * 16 * lda + co);
    }
#pragma unroll
    for (int nf = 0; nf < 2; ++nf) {
      const bf16x8 bh = *(const bf16x8*)&Whs[wn + 16 * nf + fr][koff];
      const bf16x8 bl = *(const bf16x8*)&Wls[wn + 16 * nf + fr][koff];
#pragma unroll
      for (int mf = 0; mf < 4; ++mf) {
        acc[mf][nf] = __builtin_amdgcn_mfma_f32_16x16x32_bf16(ahf[mf], bh, acc[mf][nf], 0, 0, 0);
        acc[mf][nf] = __builtin_amdgcn_mfma_f32_16x16x32_bf16(alf[mf], bh, acc[mf][nf], 0, 0, 0);
        acc[mf][nf] = __builtin_amdgcn_mfma_f32_16x16x32_bf16(ahf[mf], bl, acc[mf][nf], 0, 0, 0);
      }
    }
  }

  // epilogue: C/D layout col=lane&15, row=4*(lane>>4)+q (within 16x16 frag)
  const int r0 = wm + ((lane >> 4) << 2);
  const int c0 = n0 + wn + fr;
#pragma unroll
  for (int mf = 0; mf < 4; ++mf) {
#pragma unroll
    for (int nf = 0; nf < 2; ++nf) {
      const int col = c0 + 16 * nf;
      if (col < nrows) {
        float* p = pout + (size_t)(r0 + 16 * mf) * ldp + col;
#pragma unroll
        for (int q = 0; q < 4; ++q) p[(size_t)q * ldp] = acc[mf][nf][q];
      }
    }
  }
}

// ---------------------------------------------------------------------------
// One-shot GEMM with on-the-fly split (used only for base1 = h_n @ W_ih1ctx^T)
// (verified round-1 kernel, unchanged)
// ---------------------------------------------------------------------------
__global__ __launch_bounds__(256) void gemm_split_mfma(
    const float* __restrict__ A1, int lda1,
    const float* __restrict__ W1, int ldw1, int K1,
    int nrows, int kPerSlice,
    float* __restrict__ partial, int ldp)
{
  __shared__ unsigned short Ahs[128][40];
  __shared__ unsigned short Als[128][40];
  __shared__ unsigned short Whs[128][40];
  __shared__ unsigned short Wls[128][40];

  const int tid  = threadIdx.x;
  const int n0   = blockIdx.x * TN;
  const int ks   = blockIdx.y * kPerSlice;
  const int nc   = kPerSlice >> 5;
  float* __restrict__ pout = partial + (size_t)blockIdx.y * (size_t)Bb * ldp;

  const int lane = tid & 63;
  const int wm   = ((tid >> 6) >> 1) * 64;
  const int wn   = ((tid >> 6) & 1) * 64;
  const int sr   = tid >> 1;
  const int kh   = (tid & 1) << 4;
  const bool wok = (n0 + sr) < nrows;
  (void)K1;

  f32x4 acc[4][4];
#pragma unroll
  for (int i = 0; i < 4; ++i)
#pragma unroll
    for (int j = 0; j < 4; ++j) acc[i][j] = f32x4{0.f, 0.f, 0.f, 0.f};

  float4 areg[4], wreg[4];
  auto load_chunk = [&](int kc) {
    const float* ap = A1 + (size_t)sr * lda1 + kc + kh;
    const float* wp = W1 + (size_t)(n0 + sr) * ldw1 + kc + kh;
#pragma unroll
    for (int q = 0; q < 4; ++q) areg[q] = *(const float4*)(ap + 4 * q);
    if (wok) {
#pragma unroll
      for (int q = 0; q < 4; ++q) wreg[q] = *(const float4*)(wp + 4 * q);
    } else {
#pragma unroll
      for (int q = 0; q < 4; ++q) wreg[q] = float4{0.f, 0.f, 0.f, 0.f};
    }
  };

  load_chunk(ks);

  for (int c = 0; c < nc; ++c) {
    __syncthreads();
    {
      unsigned hA[8], lA[8], hW[8], lW[8];
#pragma unroll
      for (int q = 0; q < 4; ++q) {
        split2(areg[q].x, areg[q].y, hA[2 * q], lA[2 * q]);
        split2(areg[q].z, areg[q].w, hA[2 * q + 1], lA[2 * q + 1]);
        split2(wreg[q].x, wreg[q].y, hW[2 * q], lW[2 * q]);
        split2(wreg[q].z, wreg[q].w, hW[2 * q + 1], lW[2 * q + 1]);
      }
      *(uint4*)&Ahs[sr][kh]     = uint4{hA[0], hA[1], hA[2], hA[3]};
      *(uint4*)&Ahs[sr][kh + 8] = uint4{hA[4], hA[5], hA[6], hA[7]};
      *(uint4*)&Als[sr][kh]     = uint4{lA[0], lA[1], lA[2], lA[3]};
      *(uint4*)&Als[sr][kh + 8] = uint4{lA[4], lA[5], lA[6], lA[7]};
      *(uint4*)&Whs[sr][kh]     = uint4{hW[0], hW[1], hW[2], hW[3]};
      *(uint4*)&Whs[sr][kh + 8] = uint4{hW[4], hW[5], hW[6], hW[7]};
      *(uint4*)&Wls[sr][kh]     = uint4{lW[0], lW[1], lW[2], lW[3]};
      *(uint4*)&Wls[sr][kh + 8] = uint4{lW[4], lW[5], lW[6], lW[7]};
    }
    if (c + 1 < nc) load_chunk(ks + ((c + 1) << 5));
    __syncthreads();

    const int koff = (lane >> 4) << 3;
    const int fr   = lane & 15;
    bf16x8 bh[4], bl[4];
#pragma unroll
    for (int nf = 0; nf < 4; ++nf) {
      bh[nf] = *(const bf16x8*)&Whs[wn + 16 * nf + fr][koff];
      bl[nf] = *(const bf16x8*)&Wls[wn + 16 * nf + fr][koff];
    }
#pragma unroll
    for (int mf = 0; mf < 4; ++mf) {
      const bf16x8 ah = *(const bf16x8*)&Ahs[wm + 16 * mf + fr][koff];
      const bf16x8 al = *(const bf16x8*)&Als[wm + 16 * mf + fr][koff];
#pragma unroll
      for (int nf = 0; nf < 4; ++nf) {
        acc[mf][nf] = __builtin_amdgcn_mfma_f32_16x16x32_bf16(ah, bh[nf], acc[mf][nf], 0, 0, 0);
        acc[mf][nf] = __builtin_amdgcn_mfma_f32_16x16x32_bf16(al, bh[nf], acc[mf][nf], 0, 0, 0);
        acc[mf][nf] = __builtin_amdgcn_mfma_f32_16x16x32_bf16(ah, bl[nf], acc[mf][nf], 0, 0, 0);
      }
    }
  }

  const int r0 = wm + ((lane >> 4) << 2);
  const int c0 = n0 + wn + (lane & 15);
#pragma unroll
  for (int mf = 0; mf < 4; ++mf) {
#pragma unroll
    for (int nf = 0; nf < 4; ++nf) {
      if (n0 + wn + 16 * nf < nrows) {
        float* p = pout + (size_t)(r0 + 16 * mf) * ldp + (c0 + 16 * nf);
#pragma unroll
        for (int q = 0; q < 4; ++q) p[(size_t)q * ldp] = acc[mf][nf][q];
      }
    }
  }
}

// one-shot: split all step-loop weights into concatenated hi/lo bf16 arrays
__global__ __launch_bounds__(256) void presplit_kernel(
    const float* __restrict__ W_ih1, const float* __restrict__ W_hh1,
    const float* __restrict__ W_ih2, const float* __restrict__ W_hh2,
    const float* __restrict__ W_out,
    unsigned short* __restrict__ w1h, unsigned short* __restrict__ w1l,
    unsigned short* __restrict__ w2h, unsigned short* __restrict__ w2l,
    unsigned short* __restrict__ woh, unsigned short* __restrict__ wol)
{
  const long long tot = (long long)NW1 + NW2 + NW3;
  for (long long i = (long long)blockIdx.x * 256 + threadIdx.x; i < tot;
       i += (long long)gridDim.x * 256) {
    float src; unsigned short h, l;
    if (i < NW1) {
      const int j = (int)i, r = j / K1c, k = j - r * K1c;
      src = (k < Ee) ? W_ih1[(size_t)r * KIN1 + k] : W_hh1[(size_t)r * Hh + (k - Ee)];
      split1(src, h, l); w1h[j] = h; w1l[j] = l;
    } else if (i < (long long)NW1 + NW2) {
      const int j = (int)(i - NW1), r = j / K2c, k = j - r * K2c;
      src = (k < Hh) ? W_ih2[(size_t)r * Hh + k] : W_hh2[(size_t)r * Hh + (k - Hh)];
      split1(src, h, l); w2h[j] = h; w2l[j] = l;
    } else {
      const int j = (int)(i - NW1 - NW2);
      src = W_out[j];
      split1(src, h, l); woh[j] = h; wol[j] = l;
    }
  }
}

// zero c1,c2 (fp32) and a1/a2 hi-lo (bf16) — laid out contiguously at ws start
__global__ __launch_bounds__(256) void init_zero(uint4* __restrict__ z, int n16) {
  const int i = blockIdx.x * 256 + threadIdx.x;
  if (i < n16) z[i] = uint4{0u, 0u, 0u, 0u};
}

// x0 = drop*emb[data[:,0]] -> a1 cols 0..511 (hi/lo)
__global__ __launch_bounds__(256) void init_gather(
    const int* __restrict__ data, const float* __restrict__ drop,
    const float* __restrict__ embW,
    unsigned short* __restrict__ a1h, unsigned short* __restrict__ a1l)
{
  const int i = blockIdx.x * 256 + threadIdx.x;
  if (i < Bb * Ee) {
    const int b = i >> 9, e = i & 511;
    const int idx = data[b * Tt];
    unsigned short h, l;
    split1(drop[idx] * embW[(size_t)idx * Ee + e], h, l);
    a1h[(size_t)b * K1c + e] = h;
    a1l[(size_t)b * K1c + e] = l;
  }
}

// base1 = sum_s pl[s] + b_ih1 + b_hh1   (B x G)
__global__ __launch_bounds__(256) void base_combine(
    const float* __restrict__ pl, const float* __restrict__ b1,
    const float* __restrict__ b2, float* __restrict__ base1)
{
  const int i = blockIdx.x * 256 + threadIdx.x;
  const int g = i & (Gg - 1);
  float v = b1[g] + b2[g];
#pragma unroll
  for (int s = 0; s < SL; ++s) v += pl[(size_t)s * (Bb * Gg) + i];
  base1[i] = v;
}

// LSTM cell: sum partials (+base or biases) -> nonlinearity -> c (fp32),
// h written as bf16 hi/lo into one or two A-buffers.
__global__ __launch_bounds__(256) void cell_kernel(
    const float* __restrict__ pl,
    const float* __restrict__ base1,
    const float* __restrict__ ba, const float* __restrict__ bb,
    float* __restrict__ c,
    unsigned short* __restrict__ o1h, unsigned short* __restrict__ o1l,
    int ld1, int off1,
    unsigned short* __restrict__ o2h, unsigned short* __restrict__ o2l,
    int ld2, int off2)
{
  const int i = blockIdx.x * 256 + threadIdx.x;   // < B*H
  const int b = i >> 10, hh = i & (Hh - 1);
  float vi, vf, vg, vo;
  if (base1 != nullptr) {
    const float* bp = base1 + (size_t)b * Gg + hh;
    vi = bp[0]; vf = bp[Hh]; vg = bp[2 * Hh]; vo = bp[3 * Hh];
  } else {
    vi = ba[hh] + bb[hh];
    vf = ba[Hh + hh] + bb[Hh + hh];
    vg = ba[2 * Hh + hh] + bb[2 * Hh + hh];
    vo = ba[3 * Hh + hh] + bb[3 * Hh + hh];
  }
  const size_t rb = (size_t)b * Gg + hh;
#pragma unroll
  for (int s = 0; s < SL; ++s) {
    const float* pp = pl + (size_t)s * (Bb * Gg) + rb;
    vi += pp[0]; vf += pp[Hh]; vg += pp[2 * Hh]; vo += pp[3 * Hh];
  }
  const float si = 1.f / (1.f + expf(-vi));
  const float sf = 1.f / (1.f + expf(-vf));
  const float so = 1.f / (1.f + expf(-vo));
  const float tg = tanhf(vg);
  const float cn = sf * c[i] + si * tg;
  c[i] = cn;
  const float hn = so * tanhf(cn);
  unsigned short h, l;
  split1(hn, h, l);
  o1h[(size_t)b * ld1 + off1 + hh] = h;
  o1l[(size_t)b * ld1 + off1 + hh] = l;
  if (o2h != nullptr) {
    o2h[(size_t)b * ld2 + off2 + hh] = h;
    o2l[(size_t)b * ld2 + off2 + hh] = l;
  }
}

// logits finalize (+bias, sum SV partials) + argmax + next-input gather
__global__ __launch_bounds__(256) void argmax_kernel(
    const float* __restrict__ pv, const float* __restrict__ b_out,
    const int* __restrict__ tf_mask_t, const int* __restrict__ data, int t,
    const float* __restrict__ drop, const float* __restrict__ embW,
    float* __restrict__ out_t,
    unsigned short* __restrict__ a1h, unsigned short* __restrict__ a1l)
{
  const int b = blockIdx.x;
  const int tid = threadIdx.x;
  const float* p0 = pv + (size_t)b * Vv;
  const float* p1 = pv + (size_t)(Bb + b) * Vv;
  const float* p2 = pv + (size_t)(2 * Bb + b) * Vv;
  const float* p3 = pv + (size_t)(3 * Bb + b) * Vv;
  float* orow = out_t + (size_t)b * Vv;
  float best = -3.0e38f;
  int bi = 0;
  for (int j = tid; j < Vv; j += 256) {
    const float v = p0[j] + p1[j] + p2[j] + p3[j] + b_out[j];
    orow[j] = v;
    if (v > best) { best = v; bi = j; }
  }
  __shared__ float sv[256];
  __shared__ int si[256];
  sv[tid] = best; si[tid] = bi;
  __syncthreads();
  for (int s = 128; s > 0; s >>= 1) {
    if (tid < s) {
      const float v2 = sv[tid + s]; const int i2 = si[tid + s];
      if (v2 > sv[tid] || (v2 == sv[tid] && i2 < si[tid])) { sv[tid] = v2; si[tid] = i2; }
    }
    __syncthreads();
  }
  const int ind = si[0];
  const int mask = tf_mask_t[b];
  const int tfidx = data[b * Tt + t + 1];
  const float dm = drop[tfidx];
  for (int e = tid; e < Ee; e += 256) {
    const float val = (mask == 1) ? embW[(size_t)ind * Ee + e]
                                  : dm * embW[(size_t)tfidx * Ee + e];
    unsigned short h, l;
    split1(val, h, l);
    a1h[(size_t)b * K1c + e] = h;
    a1l[(size_t)b * K1c + e] = l;
  }
}

extern "C" void kernel_launch(void* const* d_in, const int* in_sizes, int n_in,
                              void* d_out, int out_size, void* d_ws, size_t ws_size,
                              hipStream_t stream) {
  (void)in_sizes; (void)n_in; (void)out_size; (void)ws_size;
  const float* h_n   = (const float*)d_in[0];
  const int*   data  = (const int*)d_in[1];
  const int*   tfm   = (const int*)d_in[2];
  const float* drop  = (const float*)d_in[3];
  const float* embW  = (const float*)d_in[4];
  const float* W_ih1 = (const float*)d_in[5];
  const float* W_hh1 = (const float*)d_in[6];
  const float* b_ih1 = (const float*)d_in[7];
  const float* b_hh1 = (const float*)d_in[8];
  const float* W_ih2 = (const float*)d_in[9];
  const float* W_hh2 = (const float*)d_in[10];
  const float* b_ih2 = (const float*)d_in[11];
  const float* b_hh2 = (const float*)d_in[12];
  const float* W_out = (const float*)d_in[13];
  const float* b_out = (const float*)d_in[14];
  float* out = (float*)d_out;

  // workspace layout (bytes, all sizes 256B-aligned):
  // [zeroed: c1|c2|a1h|a1l|a2h|a2l] base1 pl pv w1h w1l w2h w2l woh wol
  char* p = (char*)d_ws;
  float* c1 = (float*)p;                 p += (size_t)Bb * Hh * 4;
  float* c2 = (float*)p;                 p += (size_t)Bb * Hh * 4;
  unsigned short* a1h = (unsigned short*)p; p += (size_t)Bb * K1c * 2;
  unsigned short* a1l = (unsigned short*)p; p += (size_t)Bb * K1c * 2;
  unsigned short* a2h = (unsigned short*)p; p += (size_t)Bb * K2c * 2;
  unsigned short* a2l = (unsigned short*)p; p += (size_t)Bb * K2c * 2;
  const size_t zeroBytes = (size_t)(p - (char*)d_ws);
  float* base1 = (float*)p;              p += (size_t)Bb * Gg * 4;
  float* pl    = (float*)p;              p += (size_t)SL * Bb * Gg * 4;
  float* pv    = (float*)p;              p += (size_t)SV * Bb * Vv * 4;
  unsigned short* w1h = (unsigned short*)p; p += (size_t)NW1 * 2;
  unsigned short* w1l = (unsigned short*)p; p += (size_t)NW1 * 2;
  unsigned short* w2h = (unsigned short*)p; p += (size_t)NW2 * 2;
  unsigned short* w2l = (unsigned short*)p; p += (size_t)NW2 * 2;
  unsigned short* woh = (unsigned short*)p; p += (size_t)NW3 * 2;
  unsigned short* wol = (unsigned short*)p;

  const int n16 = (int)(zeroBytes / 16);
  init_zero<<<(n16 + 255) / 256, 256, 0, stream>>>((uint4*)d_ws, n16);
  init_gather<<<(Bb * Ee) / 256, 256, 0, stream>>>(data, drop, embW, a1h, a1l);
  presplit_kernel<<<8192, 256, 0, stream>>>(W_ih1, W_hh1, W_ih2, W_hh2, W_out,
                                            w1h, w1l, w2h, w2l, woh, wol);

  // base1 = h_n @ W_ih1[:,512:]^T + b_ih1 + b_hh1 (once)
  gemm_split_mfma<<<dim3(Gg / TN, SL), 256, 0, stream>>>(
      h_n, CTX, W_ih1 + Ee, KIN1, CTX, Gg, CTX / SL, pl, Gg);
  base_combine<<<(Bb * Gg) / 256, 256, 0, stream>>>(pl, b_ih1, b_hh1, base1);

  for (int t = 0; t < Tt - 1; ++t) {
    // layer 1: A = a1 = [x | h1], W = [W_ih1[:, :512] | W_hh1] pre-split
    gemm_bf16<<<dim3(Gg / TN, SL), 512, 0, stream>>>(
        a1h, a1l, K1c, w1h, w1l, K1c, Gg, K1c / SL, pl, Gg);
    cell_kernel<<<(Bb * Hh) / 256, 256, 0, stream>>>(
        pl, base1, nullptr, nullptr, c1,
        a1h, a1l, K1c, Ee,          // h1 -> a1 cols 512..1535
        a2h, a2l, K2c, 0);          // h1 -> a2 cols 0..1023
    // layer 2: A = a2 = [h1 | h2], W = [W_ih2 | W_hh2] pre-split
    gemm_bf16<<<dim3(Gg / TN, SL), 512, 0, stream>>>(
        a2h, a2l, K2c, w2h, w2l, K2c, Gg, K2c / SL, pl, Gg);
    cell_kernel<<<(Bb * Hh) / 256, 256, 0, stream>>>(
        pl, nullptr, b_ih2, b_hh2, c2,
        a2h, a2l, K2c, Hh,          // h2 -> a2 cols 1024..2047
        nullptr, nullptr, 0, 0);
    // logits: A = h2 (a2 cols 1024..), W = W_out pre-split
    gemm_bf16<<<dim3((Vv + TN - 1) / TN, SV), 512, 0, stream>>>(
        a2h + Hh, a2l + Hh, K2c, woh, wol, Hh, Vv, Hh / SV, pv, Vv);
    float* out_t = out + (size_t)t * Bb * Vv;
    argmax_kernel<<<Bb, 256, 0, stream>>>(pv, b_out, tfm + t * Bb, data, t,
                                          drop, embW, out_t, a1h, a1l);
  }
}